// Round 11
// baseline (277.332 us; speedup 1.0000x reference)
//
#include <hip/hip_runtime.h>

constexpr int N_NODES = 100000;
constexpr int N_FEAT  = 512;
constexpr int N_EDGES = 1600000;

// fixed-point packing for LDS u64 accumulation
constexpr float FXS = 1048576.0f;  // 2^20
constexpr float FXB = 32.0f;       // positivity bias; FXB*FXS = 2^25 exact

// binning (R8: narrow binning; R9: no dynamic scheduling; R10: extra rowdot
// workers don't help -> binning blocks do deg after a flag barrier instead)
constexpr int BSH   = 8;
constexpr int BINW  = 1 << BSH;                     // 256 nodes/bin
constexpr int NBINS = (N_NODES + BINW - 1) >> BSH;  // 391
constexpr int BCAP  = 5120;  // bin load: mean 4096, +16 sigma
constexpr int NBB   = 500;   // binning blocks
constexpr int CHUNK = N_EDGES / NBB;                // 3200 (exact)
constexpr int GRID  = 2048;
constexpr int NRB   = GRID - NBB;                   // 1548 rowdot blocks

typedef float vfloat4 __attribute__((ext_vector_type(4)));

// ws float offsets
constexpr int WS_W    = 0;                    // [0,1024) two cols of w1@w2
constexpr int WS_C    = 1024;                 // c (pad to 1056)
constexpr int WS_CUR  = 1056;                 // NBINS cursors + 1 flag (pad 512)
constexpr int WS_DEG  = WS_CUR + 512;         // deg[N] int
constexpr int WS_DINV = WS_DEG + N_NODES;     // dinv[N]
constexpr int WS_G    = WS_DINV + N_NODES;    // g[N,2] (byte%8==0)
constexpr int WS_BINS = WS_G + 2 * N_NODES;   // u32[NBINS*BCAP] ~8MB

static_assert(N_NODES % 4 == 0, "");
static_assert(NBINS + 1 <= 512, "");

// ---- kernel 1: W = w1@w2, c = b1@w2+b2, zero cursors + flag ----
__global__ void k_prep(const float* __restrict__ w1, const float* __restrict__ w2,
                       const float* __restrict__ b1, const float* __restrict__ b2,
                       float* __restrict__ ws) {
    int i = blockIdx.x * blockDim.x + threadIdx.x;
    if (i < NBINS + 1) reinterpret_cast<int*>(ws + WS_CUR)[i] = 0;
    if (i < N_FEAT) {
        float a0 = 0.f, a1 = 0.f;
        for (int m = 0; m < 128; ++m) {
            float w = w1[i * 128 + m];
            a0 += w * w2[m * 2 + 0];
            a1 += w * w2[m * 2 + 1];
        }
        ws[WS_W + i] = a0;
        ws[WS_W + 512 + i] = a1;
        if (i < 2) {
            float s = b2[i];
            for (int m = 0; m < 128; ++m) s += b1[m] * w2[m * 2 + i];
            ws[WS_C + i] = s;
        }
    }
}

// ---- kernel 2: blocks [0,NBB): bin 3200 edges -> flag barrier (binning
//      blocks only) -> deg/dinv per bin (hidden in idle slots).
//      blocks [NBB,GRID): rowdot g = x@W (R7-identical). ----
__global__ __launch_bounds__(256) void k_fused(
    const float* __restrict__ x, float* __restrict__ ws,
    const int* __restrict__ src, const int* __restrict__ dst,
    float2* __restrict__ g) {
    int b = blockIdx.x;
    int tid = threadIdx.x;
    int* gcur = reinterpret_cast<int*>(ws + WS_CUR);

    if (b < NBB) {
        // --- binning: count -> reserve -> place; edge packed into one u32 ---
        __shared__ int cnt[NBINS];
        __shared__ int offs[NBINS];
        __shared__ int cur2[NBINS];
        for (int i = tid; i < NBINS; i += 256) { cnt[i] = 0; cur2[i] = 0; }
        __syncthreads();
        int base = b * CHUNK;
        for (int e = base + tid; e < base + CHUNK; e += 256)
            atomicAdd(&cnt[dst[e] >> BSH], 1);
        __syncthreads();
        for (int i = tid; i < NBINS; i += 256) {
            int c = cnt[i];
            int pos = c ? atomicAdd(&gcur[i], c) : 0;
            offs[i] = i * BCAP + pos;
        }
        __syncthreads();
        unsigned int* bins = reinterpret_cast<unsigned int*>(ws + WS_BINS);
        for (int e = base + tid; e < base + CHUNK; e += 256) {
            int d = dst[e], s = src[e];
            int bin = d >> BSH;
            int r = atomicAdd(&cur2[bin], 1);
            bins[offs[bin] + r] = (unsigned int)s | ((unsigned int)(d & (BINW - 1)) << 17);
        }
        // --- release/acquire barrier among the NBB binning blocks only.
        // Deadlock-free under any dispatch order: rowdot blocks never wait,
        // so resident slots keep freeing up for late binning blocks. ---
        __threadfence();
        __syncthreads();
        int* flag = gcur + NBINS;
        if (tid == 0) {
            __hip_atomic_fetch_add(flag, 1, __ATOMIC_ACQ_REL, __HIP_MEMORY_SCOPE_AGENT);
            while (__hip_atomic_load(flag, __ATOMIC_ACQUIRE, __HIP_MEMORY_SCOPE_AGENT) < NBB)
                __builtin_amdgcn_s_sleep(2);
        }
        __syncthreads();
        __threadfence();   // don't serve stale bins/cursors from caches
        // --- deg/dinv for bin b (blocks 391..499 exit) ---
        if (b < NBINS) {
            int n = min(__hip_atomic_load(&gcur[b], __ATOMIC_RELAXED,
                                          __HIP_MEMORY_SCOPE_AGENT), BCAP);
            if (tid < BINW) cnt[tid] = 0;
            __syncthreads();
            const unsigned int* bb = bins + b * BCAP;
            for (int i = tid; i < n; i += 256)
                atomicAdd(&cnt[bb[i] >> 17], 1);
            __syncthreads();
            int d = (b << BSH) + tid;
            if (tid < BINW && d < N_NODES) {
                int dg = cnt[tid] + 1;               // + self-loop
                reinterpret_cast<int*>(ws + WS_DEG)[d] = dg;
                ws[WS_DINV + d] = rsqrtf((float)dg);
            }
        }
        return;
    }

    // --- rowdot: 4 rows per iteration, 16 lanes per row (R7-identical) ---
    int rb = b - NBB;
    const vfloat4* W0q = reinterpret_cast<const vfloat4*>(ws + WS_W);
    const vfloat4* W1q = reinterpret_cast<const vfloat4*>(ws + WS_W + 512);
    int lane = tid & 63;
    int wave = tid >> 6;
    int j = lane & 15, i4 = lane >> 4;

    vfloat4 w0[8], w1[8];
    #pragma unroll
    for (int k = 0; k < 8; ++k) {
        w0[k] = W0q[k * 16 + j];
        w1[k] = W1q[k * 16 + j];
    }

    int wid = rb * 4 + wave;
    int nw  = NRB * 4;                    // 6192
    constexpr int NQ = N_NODES / 4;       // 25000
    for (int q = wid; q < NQ; q += nw) {
        int row = q * 4 + i4;
        const vfloat4* xr = reinterpret_cast<const vfloat4*>(x + (size_t)row * N_FEAT);
        vfloat4 xv[8];
        #pragma unroll
        for (int k = 0; k < 8; ++k)
            xv[k] = __builtin_nontemporal_load(&xr[k * 16 + j]);
        float a0 = 0.f, a1 = 0.f;
        #pragma unroll
        for (int k = 0; k < 8; ++k) {
            a0 += xv[k].x*w0[k].x + xv[k].y*w0[k].y + xv[k].z*w0[k].z + xv[k].w*w0[k].w;
            a1 += xv[k].x*w1[k].x + xv[k].y*w1[k].y + xv[k].z*w1[k].z + xv[k].w*w1[k].w;
        }
        #pragma unroll
        for (int off = 1; off <= 8; off <<= 1) {
            a0 += __shfl_xor(a0, off);
            a1 += __shfl_xor(a1, off);
        }
        if (j == 0) g[row] = make_float2(a0, a1);
    }
}

// ---- kernel 3: per-bin LDS u64 fixed-point accumulation (addend computed
//      on the fly from g[s], dinv[s] — both L2-resident); finalize ----
__global__ __launch_bounds__(256) void k_pass2(float* __restrict__ ws,
                                               float2* __restrict__ out) {
    int b = blockIdx.x;
    const int* gcur = reinterpret_cast<const int*>(ws + WS_CUR);
    const unsigned int* bins = reinterpret_cast<const unsigned int*>(ws + WS_BINS) + b * BCAP;
    const int* deg = reinterpret_cast<const int*>(ws + WS_DEG);
    const float* dinv = ws + WS_DINV;
    const float2* g = reinterpret_cast<const float2*>(ws + WS_G);
    int n = min(gcur[b], BCAP);
    __shared__ unsigned long long acc[BINW];
    acc[threadIdx.x] = 0ull;
    __syncthreads();
    for (int i = threadIdx.x; i < n; i += 256) {
        unsigned int p = bins[i];
        int s = (int)(p & 0x1FFFFu);
        float2 gv = g[s];
        float di = dinv[s];
        unsigned int lo = (unsigned int)__float2int_rn((gv.x * di + FXB) * FXS);
        unsigned int hi = (unsigned int)__float2int_rn((gv.y * di + FXB) * FXS);
        atomicAdd(&acc[p >> 17], ((unsigned long long)hi << 32) | (unsigned long long)lo);
    }
    __syncthreads();
    int d = (b << BSH) + threadIdx.x;
    if (d < N_NODES) {
        unsigned long long a = acc[threadIdx.x];
        long long cnt = (long long)(deg[d] - 1);     // in-edges (excl self-loop)
        long long bias = cnt << 25;                  // exact: cnt * FXB*FXS
        long long lo = (long long)(a & 0xFFFFFFFFull) - bias;
        long long hi = (long long)(a >> 32) - bias;
        float di = dinv[d];
        float2 gv = g[d];
        float s0 = (float)lo * (1.0f / FXS) + gv.x * di;   // + self-loop term
        float s1 = (float)hi * (1.0f / FXS) + gv.y * di;
        out[d] = make_float2(di * s0 + ws[WS_C + 0], di * s1 + ws[WS_C + 1]);
    }
}

extern "C" void kernel_launch(void* const* d_in, const int* in_sizes, int n_in,
                              void* d_out, int out_size, void* d_ws, size_t ws_size,
                              hipStream_t stream) {
    const float* x  = (const float*)d_in[0];
    const float* w1 = (const float*)d_in[1];
    const float* b1 = (const float*)d_in[2];
    const float* w2 = (const float*)d_in[3];
    const float* b2 = (const float*)d_in[4];
    const int*   ei = (const int*)d_in[5];   // [2, E]: src row then dst row
    float* ws = (float*)d_ws;

    float2* g = (float2*)(ws + WS_G);

    k_prep<<<2, 256, 0, stream>>>(w1, w2, b1, b2, ws);
    k_fused<<<GRID, 256, 0, stream>>>(x, ws, ei, ei + N_EDGES, g);
    k_pass2<<<NBINS, 256, 0, stream>>>(ws, (float2*)d_out);
}

// Round 12
// 83.518 us; speedup vs baseline: 3.3206x; 3.3206x over previous
//
#include <hip/hip_runtime.h>

constexpr int N_NODES = 100000;
constexpr int N_FEAT  = 512;
constexpr int N_EDGES = 1600000;

// fixed-point packing for LDS u64 accumulation
constexpr float FXS = 1048576.0f;  // 2^20
constexpr float FXB = 32.0f;       // positivity bias; FXB*FXS = 2^25 exact

// binning (R8: narrow binning; R9: no dynamic scheduling; R6/R11: NO in-kernel
// inter-block barriers — ever)
constexpr int BSH   = 8;
constexpr int BINW  = 1 << BSH;                     // 256 nodes/bin
constexpr int NBINS = (N_NODES + BINW - 1) >> BSH;  // 391
constexpr int BCAP  = 5120;  // bin load: mean 4096, +16 sigma
constexpr int NBB   = 500;   // binning blocks
constexpr int CHUNK = N_EDGES / NBB;                // 3200 (exact)
constexpr int GRID  = 2048;
constexpr int NRB   = GRID - NBB;                   // 1548 rowdot blocks

typedef float vfloat4 __attribute__((ext_vector_type(4)));

// ws float offsets
constexpr int WS_W    = 0;                    // [0,1024) two cols of w1@w2
constexpr int WS_C    = 1024;                 // c (pad to 1056)
constexpr int WS_CUR  = 1056;                 // NBINS cursors (pad 512)
constexpr int WS_DEG  = WS_CUR + 512;         // deg[N] int
constexpr int WS_DINV = WS_DEG + N_NODES;     // dinv[N]
constexpr int WS_G    = WS_DINV + N_NODES;    // g[N,2] (byte%8==0)
constexpr int WS_FXP  = WS_G + 2 * N_NODES;   // u64[N] packed addends
constexpr int WS_BINS = WS_FXP + 2 * N_NODES; // u32[NBINS*BCAP] ~8MB

static_assert((WS_FXP * 4) % 8 == 0, "fxp alignment");
static_assert(N_NODES % 4 == 0, "");

// ---- kernel 1: W = w1@w2, c = b1@w2+b2, zero cursors ----
__global__ void k_prep(const float* __restrict__ w1, const float* __restrict__ w2,
                       const float* __restrict__ b1, const float* __restrict__ b2,
                       float* __restrict__ ws) {
    int i = blockIdx.x * blockDim.x + threadIdx.x;
    if (i < NBINS) reinterpret_cast<int*>(ws + WS_CUR)[i] = 0;
    if (i < N_FEAT) {
        float a0 = 0.f, a1 = 0.f;
        for (int m = 0; m < 128; ++m) {
            float w = w1[i * 128 + m];
            a0 += w * w2[m * 2 + 0];
            a1 += w * w2[m * 2 + 1];
        }
        ws[WS_W + i] = a0;
        ws[WS_W + 512 + i] = a1;
        if (i < 2) {
            float s = b2[i];
            for (int m = 0; m < 128; ++m) s += b1[m] * w2[m * 2 + i];
            ws[WS_C + i] = s;
        }
    }
}

// ---- kernel 2 (fused): blocks [0,NBB) bin edges by dst; rest rowdot g=x@W ----
// A/B vs R7: plain loads instead of __builtin_nontemporal_load (NT suspected of
// evicting x from L3 between replays; R11 showed 110MB/replay HBM re-fetch).
__global__ __launch_bounds__(256) void k_fused(
    const float* __restrict__ x, float* __restrict__ ws,
    const int* __restrict__ src, const int* __restrict__ dst,
    float2* __restrict__ g) {
    int b = blockIdx.x;
    int tid = threadIdx.x;

    if (b < NBB) {
        // --- binning: count -> reserve -> place; edge packed into one u32 ---
        __shared__ int cnt[NBINS];
        __shared__ int offs[NBINS];
        __shared__ int cur2[NBINS];
        for (int i = tid; i < NBINS; i += 256) { cnt[i] = 0; cur2[i] = 0; }
        __syncthreads();
        int base = b * CHUNK;
        for (int e = base + tid; e < base + CHUNK; e += 256)
            atomicAdd(&cnt[dst[e] >> BSH], 1);
        __syncthreads();
        int* gcur = reinterpret_cast<int*>(ws + WS_CUR);
        for (int i = tid; i < NBINS; i += 256) {
            int c = cnt[i];
            int pos = c ? atomicAdd(&gcur[i], c) : 0;
            offs[i] = i * BCAP + pos;
        }
        __syncthreads();
        unsigned int* bins = reinterpret_cast<unsigned int*>(ws + WS_BINS);
        for (int e = base + tid; e < base + CHUNK; e += 256) {
            int d = dst[e], s = src[e];
            int bin = d >> BSH;
            int r = atomicAdd(&cur2[bin], 1);
            bins[offs[bin] + r] = (unsigned int)s | ((unsigned int)(d & (BINW - 1)) << 17);
        }
        return;
    }
    // --- rowdot: 4 rows per wave-iteration, 16 lanes per row ---
    int rb = b - NBB;
    const vfloat4* W0q = reinterpret_cast<const vfloat4*>(ws + WS_W);
    const vfloat4* W1q = reinterpret_cast<const vfloat4*>(ws + WS_W + 512);
    int lane = tid & 63;
    int wave = tid >> 6;
    int j = lane & 15, i4 = lane >> 4;

    vfloat4 w0[8], w1[8];
    #pragma unroll
    for (int k = 0; k < 8; ++k) {
        w0[k] = W0q[k * 16 + j];
        w1[k] = W1q[k * 16 + j];
    }

    int wid = rb * 4 + wave;
    int nw  = NRB * 4;                    // 6192
    constexpr int NQ = N_NODES / 4;       // 25000
    for (int q = wid; q < NQ; q += nw) {
        int row = q * 4 + i4;
        const vfloat4* xr = reinterpret_cast<const vfloat4*>(x + (size_t)row * N_FEAT);
        vfloat4 xv[8];
        #pragma unroll
        for (int k = 0; k < 8; ++k)
            xv[k] = xr[k * 16 + j];
        float a0 = 0.f, a1 = 0.f;
        #pragma unroll
        for (int k = 0; k < 8; ++k) {
            a0 += xv[k].x*w0[k].x + xv[k].y*w0[k].y + xv[k].z*w0[k].z + xv[k].w*w0[k].w;
            a1 += xv[k].x*w1[k].x + xv[k].y*w1[k].y + xv[k].z*w1[k].z + xv[k].w*w1[k].w;
        }
        #pragma unroll
        for (int off = 1; off <= 8; off <<= 1) {
            a0 += __shfl_xor(a0, off);
            a1 += __shfl_xor(a1, off);
        }
        if (j == 0) g[row] = make_float2(a0, a1);
    }
}

// ---- kernel 3: per-bin degree count; write deg, dinv, packed addend fxp ----
__global__ __launch_bounds__(256) void k_deg(float* __restrict__ ws) {
    int b = blockIdx.x;
    const int* gcur = reinterpret_cast<const int*>(ws + WS_CUR);
    const unsigned int* bins = reinterpret_cast<const unsigned int*>(ws + WS_BINS) + b * BCAP;
    int n = min(gcur[b], BCAP);
    __shared__ int cnt[BINW];
    cnt[threadIdx.x] = 0;
    __syncthreads();
    for (int i = threadIdx.x; i < n; i += 256)
        atomicAdd(&cnt[bins[i] >> 17], 1);
    __syncthreads();
    int d = (b << BSH) + threadIdx.x;
    if (d < N_NODES) {
        int dg = cnt[threadIdx.x] + 1;               // + self-loop
        reinterpret_cast<int*>(ws + WS_DEG)[d] = dg;
        float di = rsqrtf((float)dg);
        ws[WS_DINV + d] = di;
        float2 gv = reinterpret_cast<const float2*>(ws + WS_G)[d];
        unsigned int lo = (unsigned int)__float2int_rn((gv.x * di + FXB) * FXS);
        unsigned int hi = (unsigned int)__float2int_rn((gv.y * di + FXB) * FXS);
        reinterpret_cast<unsigned long long*>(ws + WS_FXP)[d] =
            ((unsigned long long)hi << 32) | (unsigned long long)lo;
    }
}

// ---- kernel 4: per-bin LDS u64 accumulation of fxp[src]; finalize ----
__global__ __launch_bounds__(256) void k_pass2(float* __restrict__ ws,
                                               float2* __restrict__ out) {
    int b = blockIdx.x;
    const int* gcur = reinterpret_cast<const int*>(ws + WS_CUR);
    const unsigned int* bins = reinterpret_cast<const unsigned int*>(ws + WS_BINS) + b * BCAP;
    const int* deg = reinterpret_cast<const int*>(ws + WS_DEG);
    const float* dinv = ws + WS_DINV;
    const unsigned long long* fxp = reinterpret_cast<const unsigned long long*>(ws + WS_FXP);
    int n = min(gcur[b], BCAP);
    __shared__ unsigned long long acc[BINW];
    acc[threadIdx.x] = 0ull;
    __syncthreads();
    for (int i = threadIdx.x; i < n; i += 256) {
        unsigned int p = bins[i];
        atomicAdd(&acc[p >> 17], fxp[p & 0x1FFFFu]);
    }
    __syncthreads();
    int d = (b << BSH) + threadIdx.x;
    if (d < N_NODES) {
        unsigned long long a = acc[threadIdx.x] + fxp[d];   // + self-loop addend
        long long dg = (long long)deg[d];
        long long bias = dg << 25;                           // exact: deg * FXB*FXS
        long long lo = (long long)(a & 0xFFFFFFFFull) - bias;
        long long hi = (long long)(a >> 32) - bias;
        float di = dinv[d];
        out[d] = make_float2(di * ((float)lo * (1.0f / FXS)) + ws[WS_C + 0],
                             di * ((float)hi * (1.0f / FXS)) + ws[WS_C + 1]);
    }
}

extern "C" void kernel_launch(void* const* d_in, const int* in_sizes, int n_in,
                              void* d_out, int out_size, void* d_ws, size_t ws_size,
                              hipStream_t stream) {
    const float* x  = (const float*)d_in[0];
    const float* w1 = (const float*)d_in[1];
    const float* b1 = (const float*)d_in[2];
    const float* w2 = (const float*)d_in[3];
    const float* b2 = (const float*)d_in[4];
    const int*   ei = (const int*)d_in[5];   // [2, E]: src row then dst row
    float* ws = (float*)d_ws;

    float2* g = (float2*)(ws + WS_G);

    k_prep<<<2, 256, 0, stream>>>(w1, w2, b1, b2, ws);
    k_fused<<<GRID, 256, 0, stream>>>(x, ws, ei, ei + N_EDGES, g);
    k_deg<<<NBINS, 256, 0, stream>>>(ws);
    k_pass2<<<NBINS, 256, 0, stream>>>(ws, (float2*)d_out);
}

// Round 13
// 80.338 us; speedup vs baseline: 3.4521x; 1.0396x over previous
//
#include <hip/hip_runtime.h>

constexpr int N_NODES = 100000;
constexpr int N_FEAT  = 512;
constexpr int N_EDGES = 1600000;

// fixed-point packing for LDS u64 accumulation
constexpr float FXS = 1048576.0f;  // 2^20
constexpr float FXB = 32.0f;       // positivity bias; FXB*FXS = 2^25 exact

// binning (R8: narrow; R9: no dynamic sched; R6/R11: no inter-block barriers;
// R13: XCD-sharded bins to kill cross-XCD cache-line ping-pong on the scatter)
constexpr int BSH    = 8;
constexpr int BINW   = 1 << BSH;                     // 256 nodes/bin
constexpr int NBINS  = (N_NODES + BINW - 1) >> BSH;  // 391
constexpr int NSH    = 8;                            // shards (≈ XCDs)
constexpr int BCAP_S = 768;   // per-(bin,shard): mean 516, +11 sigma
constexpr int NBB    = 500;   // binning blocks
constexpr int CHUNK  = N_EDGES / NBB;                // 3200 (exact)
constexpr int GRID   = 2048;
constexpr int NRB    = GRID - NBB;                   // 1548 rowdot blocks
constexpr int NCUR   = NBINS * NSH;                  // 3128 cursors

typedef float vfloat4 __attribute__((ext_vector_type(4)));

// ws float offsets
constexpr int WS_W    = 0;                    // [0,1024) two cols of w1@w2
constexpr int WS_C    = 1024;                 // c (pad to 1056)
constexpr int WS_CUR  = 1056;                 // NCUR cursors (pad 3200)
constexpr int WS_DEG  = WS_CUR + 3200;        // deg[N] int
constexpr int WS_DINV = WS_DEG + N_NODES;     // dinv[N]
constexpr int WS_G    = WS_DINV + N_NODES;    // g[N,2] (byte%8==0)
constexpr int WS_FXP  = WS_G + 2 * N_NODES;   // u64[N] packed addends
constexpr int WS_BINS = WS_FXP + 2 * N_NODES; // u32[NCUR*BCAP_S] ~9.6MB

static_assert((WS_G * 4) % 8 == 0, "g alignment");
static_assert((WS_FXP * 4) % 8 == 0, "fxp alignment");
static_assert(N_NODES % 4 == 0, "");

// ---- kernel 1: W = w1@w2, c = b1@w2+b2, zero cursors ----
__global__ void k_prep(const float* __restrict__ w1, const float* __restrict__ w2,
                       const float* __restrict__ b1, const float* __restrict__ b2,
                       float* __restrict__ ws) {
    int i = blockIdx.x * blockDim.x + threadIdx.x;
    if (i < NCUR) reinterpret_cast<int*>(ws + WS_CUR)[i] = 0;
    if (i < N_FEAT) {
        float a0 = 0.f, a1 = 0.f;
        for (int m = 0; m < 128; ++m) {
            float w = w1[i * 128 + m];
            a0 += w * w2[m * 2 + 0];
            a1 += w * w2[m * 2 + 1];
        }
        ws[WS_W + i] = a0;
        ws[WS_W + 512 + i] = a1;
        if (i < 2) {
            float s = b2[i];
            for (int m = 0; m < 128; ++m) s += b1[m] * w2[m * 2 + i];
            ws[WS_C + i] = s;
        }
    }
}

// ---- kernel 2 (fused): blocks [0,NBB) bin edges into their XCD shard;
//      blocks [NBB,GRID) rowdot g = x@W (R12-identical). ----
__global__ __launch_bounds__(256) void k_fused(
    const float* __restrict__ x, float* __restrict__ ws,
    const int* __restrict__ src, const int* __restrict__ dst,
    float2* __restrict__ g) {
    int b = blockIdx.x;
    int tid = threadIdx.x;

    if (b < NBB) {
        // --- binning: count -> reserve (sharded) -> place ---
        __shared__ int cnt[NBINS];
        __shared__ int offs[NBINS];
        __shared__ int cur2[NBINS];
        int sg = b & (NSH - 1);          // shard = likely XCD (blockIdx round-robin)
        for (int i = tid; i < NBINS; i += 256) { cnt[i] = 0; cur2[i] = 0; }
        __syncthreads();
        int base = b * CHUNK;
        for (int e = base + tid; e < base + CHUNK; e += 256)
            atomicAdd(&cnt[dst[e] >> BSH], 1);
        __syncthreads();
        int* gcur = reinterpret_cast<int*>(ws + WS_CUR);
        for (int i = tid; i < NBINS; i += 256) {
            int c = cnt[i];
            int pos = c ? atomicAdd(&gcur[i * NSH + sg], c) : 0;
            offs[i] = (i * NSH + sg) * BCAP_S + pos;
        }
        __syncthreads();
        unsigned int* bins = reinterpret_cast<unsigned int*>(ws + WS_BINS);
        for (int e = base + tid; e < base + CHUNK; e += 256) {
            int d = dst[e], s = src[e];
            int bin = d >> BSH;
            int r = atomicAdd(&cur2[bin], 1);
            bins[offs[bin] + r] = (unsigned int)s | ((unsigned int)(d & (BINW - 1)) << 17);
        }
        return;
    }
    // --- rowdot: 4 rows per wave-iteration, 16 lanes per row ---
    int rb = b - NBB;
    const vfloat4* W0q = reinterpret_cast<const vfloat4*>(ws + WS_W);
    const vfloat4* W1q = reinterpret_cast<const vfloat4*>(ws + WS_W + 512);
    int lane = tid & 63;
    int wave = tid >> 6;
    int j = lane & 15, i4 = lane >> 4;

    vfloat4 w0[8], w1[8];
    #pragma unroll
    for (int k = 0; k < 8; ++k) {
        w0[k] = W0q[k * 16 + j];
        w1[k] = W1q[k * 16 + j];
    }

    int wid = rb * 4 + wave;
    int nw  = NRB * 4;                    // 6192
    constexpr int NQ = N_NODES / 4;       // 25000
    for (int q = wid; q < NQ; q += nw) {
        int row = q * 4 + i4;
        const vfloat4* xr = reinterpret_cast<const vfloat4*>(x + (size_t)row * N_FEAT);
        vfloat4 xv[8];
        #pragma unroll
        for (int k = 0; k < 8; ++k)
            xv[k] = xr[k * 16 + j];
        float a0 = 0.f, a1 = 0.f;
        #pragma unroll
        for (int k = 0; k < 8; ++k) {
            a0 += xv[k].x*w0[k].x + xv[k].y*w0[k].y + xv[k].z*w0[k].z + xv[k].w*w0[k].w;
            a1 += xv[k].x*w1[k].x + xv[k].y*w1[k].y + xv[k].z*w1[k].z + xv[k].w*w1[k].w;
        }
        #pragma unroll
        for (int off = 1; off <= 8; off <<= 1) {
            a0 += __shfl_xor(a0, off);
            a1 += __shfl_xor(a1, off);
        }
        if (j == 0) g[row] = make_float2(a0, a1);
    }
}

// ---- kernel 3: per-bin degree count over 8 shards; deg, dinv, fxp ----
__global__ __launch_bounds__(256) void k_deg(float* __restrict__ ws) {
    int b = blockIdx.x;
    const int* gcur = reinterpret_cast<const int*>(ws + WS_CUR);
    const unsigned int* bins = reinterpret_cast<const unsigned int*>(ws + WS_BINS);
    __shared__ int cnt[BINW];
    cnt[threadIdx.x] = 0;
    __syncthreads();
    #pragma unroll
    for (int sg = 0; sg < NSH; ++sg) {
        int cell = b * NSH + sg;
        int n = min(gcur[cell], BCAP_S);
        const unsigned int* bb = bins + (size_t)cell * BCAP_S;
        for (int i = threadIdx.x; i < n; i += 256)
            atomicAdd(&cnt[bb[i] >> 17], 1);
    }
    __syncthreads();
    int d = (b << BSH) + threadIdx.x;
    if (d < N_NODES) {
        int dg = cnt[threadIdx.x] + 1;               // + self-loop
        reinterpret_cast<int*>(ws + WS_DEG)[d] = dg;
        float di = rsqrtf((float)dg);
        ws[WS_DINV + d] = di;
        float2 gv = reinterpret_cast<const float2*>(ws + WS_G)[d];
        unsigned int lo = (unsigned int)__float2int_rn((gv.x * di + FXB) * FXS);
        unsigned int hi = (unsigned int)__float2int_rn((gv.y * di + FXB) * FXS);
        reinterpret_cast<unsigned long long*>(ws + WS_FXP)[d] =
            ((unsigned long long)hi << 32) | (unsigned long long)lo;
    }
}

// ---- kernel 4: per-bin LDS u64 accumulation of fxp[src] over shards ----
__global__ __launch_bounds__(256) void k_pass2(float* __restrict__ ws,
                                               float2* __restrict__ out) {
    int b = blockIdx.x;
    const int* gcur = reinterpret_cast<const int*>(ws + WS_CUR);
    const unsigned int* bins = reinterpret_cast<const unsigned int*>(ws + WS_BINS);
    const int* deg = reinterpret_cast<const int*>(ws + WS_DEG);
    const float* dinv = ws + WS_DINV;
    const unsigned long long* fxp = reinterpret_cast<const unsigned long long*>(ws + WS_FXP);
    __shared__ unsigned long long acc[BINW];
    acc[threadIdx.x] = 0ull;
    __syncthreads();
    #pragma unroll
    for (int sg = 0; sg < NSH; ++sg) {
        int cell = b * NSH + sg;
        int n = min(gcur[cell], BCAP_S);
        const unsigned int* bb = bins + (size_t)cell * BCAP_S;
        for (int i = threadIdx.x; i < n; i += 256) {
            unsigned int p = bb[i];
            atomicAdd(&acc[p >> 17], fxp[p & 0x1FFFFu]);
        }
    }
    __syncthreads();
    int d = (b << BSH) + threadIdx.x;
    if (d < N_NODES) {
        unsigned long long a = acc[threadIdx.x] + fxp[d];   // + self-loop addend
        long long dg = (long long)deg[d];
        long long bias = dg << 25;                           // exact: deg * FXB*FXS
        long long lo = (long long)(a & 0xFFFFFFFFull) - bias;
        long long hi = (long long)(a >> 32) - bias;
        float di = dinv[d];
        out[d] = make_float2(di * ((float)lo * (1.0f / FXS)) + ws[WS_C + 0],
                             di * ((float)hi * (1.0f / FXS)) + ws[WS_C + 1]);
    }
}

extern "C" void kernel_launch(void* const* d_in, const int* in_sizes, int n_in,
                              void* d_out, int out_size, void* d_ws, size_t ws_size,
                              hipStream_t stream) {
    const float* x  = (const float*)d_in[0];
    const float* w1 = (const float*)d_in[1];
    const float* b1 = (const float*)d_in[2];
    const float* w2 = (const float*)d_in[3];
    const float* b2 = (const float*)d_in[4];
    const int*   ei = (const int*)d_in[5];   // [2, E]: src row then dst row
    float* ws = (float*)d_ws;

    float2* g = (float2*)(ws + WS_G);

    k_prep<<<13, 256, 0, stream>>>(w1, w2, b1, b2, ws);
    k_fused<<<GRID, 256, 0, stream>>>(x, ws, ei, ei + N_EDGES, g);
    k_deg<<<NBINS, 256, 0, stream>>>(ws);
    k_pass2<<<NBINS, 256, 0, stream>>>(ws, (float2*)d_out);
}

// Round 14
// 79.911 us; speedup vs baseline: 3.4705x; 1.0053x over previous
//
#include <hip/hip_runtime.h>

constexpr int N_NODES = 100000;
constexpr int N_FEAT  = 512;
constexpr int N_EDGES = 1600000;

// fixed-point packing for LDS u64 accumulation
constexpr float FXS = 1048576.0f;  // 2^20
constexpr float FXB = 32.0f;       // positivity bias; FXB*FXS = 2^25 exact

// binning (R8: narrow; R9: no dynamic sched; R6/R11: no inter-block barriers;
// R13: XCD-sharded bins; R14: W staged in LDS — VGPR=60 proved W was being
// re-loaded through L1 every iteration, 2/3 of the loop's L1 traffic)
constexpr int BSH    = 8;
constexpr int BINW   = 1 << BSH;                     // 256 nodes/bin
constexpr int NBINS  = (N_NODES + BINW - 1) >> BSH;  // 391
constexpr int NSH    = 8;                            // shards (≈ XCDs)
constexpr int BCAP_S = 768;   // per-(bin,shard): mean 516, +11 sigma
constexpr int NBB    = 500;   // binning blocks
constexpr int CHUNK  = N_EDGES / NBB;                // 3200 (exact)
constexpr int GRID   = 2048;
constexpr int NRB    = GRID - NBB;                   // 1548 rowdot blocks
constexpr int NCUR   = NBINS * NSH;                  // 3128 cursors

typedef float vfloat4 __attribute__((ext_vector_type(4)));

// ws float offsets
constexpr int WS_W    = 0;                    // [0,1024) two cols of w1@w2
constexpr int WS_C    = 1024;                 // c (pad to 1056)
constexpr int WS_CUR  = 1056;                 // NCUR cursors (pad 3200)
constexpr int WS_DEG  = WS_CUR + 3200;        // deg[N] int
constexpr int WS_DINV = WS_DEG + N_NODES;     // dinv[N]
constexpr int WS_G    = WS_DINV + N_NODES;    // g[N,2] (byte%8==0)
constexpr int WS_FXP  = WS_G + 2 * N_NODES;   // u64[N] packed addends
constexpr int WS_BINS = WS_FXP + 2 * N_NODES; // u32[NCUR*BCAP_S] ~9.6MB

static_assert((WS_G * 4) % 8 == 0, "g alignment");
static_assert((WS_FXP * 4) % 8 == 0, "fxp alignment");
static_assert(N_NODES % 4 == 0, "");

// ---- kernel 1: W = w1@w2, c = b1@w2+b2, zero cursors ----
__global__ void k_prep(const float* __restrict__ w1, const float* __restrict__ w2,
                       const float* __restrict__ b1, const float* __restrict__ b2,
                       float* __restrict__ ws) {
    int i = blockIdx.x * blockDim.x + threadIdx.x;
    if (i < NCUR) reinterpret_cast<int*>(ws + WS_CUR)[i] = 0;
    if (i < N_FEAT) {
        float a0 = 0.f, a1 = 0.f;
        for (int m = 0; m < 128; ++m) {
            float w = w1[i * 128 + m];
            a0 += w * w2[m * 2 + 0];
            a1 += w * w2[m * 2 + 1];
        }
        ws[WS_W + i] = a0;
        ws[WS_W + 512 + i] = a1;
        if (i < 2) {
            float s = b2[i];
            for (int m = 0; m < 128; ++m) s += b1[m] * w2[m * 2 + i];
            ws[WS_C + i] = s;
        }
    }
}

// ---- kernel 2 (fused): blocks [0,NBB) bin edges into their XCD shard;
//      blocks [NBB,GRID) rowdot g = x@W with W staged in LDS. ----
__global__ __launch_bounds__(256) void k_fused(
    const float* __restrict__ x, float* __restrict__ ws,
    const int* __restrict__ src, const int* __restrict__ dst,
    float2* __restrict__ g) {
    int b = blockIdx.x;
    int tid = threadIdx.x;

    __shared__ vfloat4 Wlds[256];   // [0,128) col0, [128,256) col1 — 4 KB

    if (b < NBB) {
        // --- binning: count -> reserve (sharded) -> place ---
        __shared__ int cnt[NBINS];
        __shared__ int offs[NBINS];
        __shared__ int cur2[NBINS];
        int sg = b & (NSH - 1);          // shard = likely XCD (round-robin dispatch)
        for (int i = tid; i < NBINS; i += 256) { cnt[i] = 0; cur2[i] = 0; }
        __syncthreads();
        int base = b * CHUNK;
        for (int e = base + tid; e < base + CHUNK; e += 256)
            atomicAdd(&cnt[dst[e] >> BSH], 1);
        __syncthreads();
        int* gcur = reinterpret_cast<int*>(ws + WS_CUR);
        for (int i = tid; i < NBINS; i += 256) {
            int c = cnt[i];
            int pos = c ? atomicAdd(&gcur[i * NSH + sg], c) : 0;
            offs[i] = (i * NSH + sg) * BCAP_S + pos;
        }
        __syncthreads();
        unsigned int* bins = reinterpret_cast<unsigned int*>(ws + WS_BINS);
        for (int e = base + tid; e < base + CHUNK; e += 256) {
            int d = dst[e], s = src[e];
            int bin = d >> BSH;
            int r = atomicAdd(&cur2[bin], 1);
            bins[offs[bin] + r] = (unsigned int)s | ((unsigned int)(d & (BINW - 1)) << 17);
        }
        return;
    }
    // --- stage W into LDS once per block ---
    {
        const vfloat4* Wq = reinterpret_cast<const vfloat4*>(ws + WS_W);
        if (tid < 256) Wlds[tid] = Wq[tid];   // 256 vfloat4 = 1024 floats
        __syncthreads();
    }
    // --- rowdot: 4 rows per wave-iteration, 16 lanes per row ---
    int rb = b - NBB;
    int lane = tid & 63;
    int wave = tid >> 6;
    int j = lane & 15, i4 = lane >> 4;
    const vfloat4* W0l = Wlds;          // col0: [k*16+j], k in [0,8)
    const vfloat4* W1l = Wlds + 128;    // col1

    int wid = rb * 4 + wave;
    int nw  = NRB * 4;                    // 6192
    constexpr int NQ = N_NODES / 4;       // 25000
    for (int q = wid; q < NQ; q += nw) {
        int row = q * 4 + i4;
        const vfloat4* xr = reinterpret_cast<const vfloat4*>(x + (size_t)row * N_FEAT);
        vfloat4 xv[8];
        #pragma unroll
        for (int k = 0; k < 8; ++k)
            xv[k] = xr[k * 16 + j];
        float a0 = 0.f, a1 = 0.f;
        #pragma unroll
        for (int k = 0; k < 8; ++k) {
            vfloat4 w0 = W0l[k * 16 + j];
            vfloat4 w1 = W1l[k * 16 + j];
            a0 += xv[k].x*w0.x + xv[k].y*w0.y + xv[k].z*w0.z + xv[k].w*w0.w;
            a1 += xv[k].x*w1.x + xv[k].y*w1.y + xv[k].z*w1.z + xv[k].w*w1.w;
        }
        #pragma unroll
        for (int off = 1; off <= 8; off <<= 1) {
            a0 += __shfl_xor(a0, off);
            a1 += __shfl_xor(a1, off);
        }
        if (j == 0) g[row] = make_float2(a0, a1);
    }
}

// ---- kernel 3: per-bin degree count over 8 shards; deg, dinv, fxp ----
__global__ __launch_bounds__(512) void k_deg(float* __restrict__ ws) {
    int b = blockIdx.x;
    int tid = threadIdx.x;
    const int* gcur = reinterpret_cast<const int*>(ws + WS_CUR);
    const unsigned int* bins = reinterpret_cast<const unsigned int*>(ws + WS_BINS);
    __shared__ int cnt[BINW];
    if (tid < BINW) cnt[tid] = 0;
    __syncthreads();
    #pragma unroll
    for (int sg = 0; sg < NSH; ++sg) {
        int cell = b * NSH + sg;
        int n = min(gcur[cell], BCAP_S);
        const unsigned int* bb = bins + (size_t)cell * BCAP_S;
        for (int i = tid; i < n; i += 512)
            atomicAdd(&cnt[bb[i] >> 17], 1);
    }
    __syncthreads();
    int d = (b << BSH) + tid;
    if (tid < BINW && d < N_NODES) {
        int dg = cnt[tid] + 1;                       // + self-loop
        reinterpret_cast<int*>(ws + WS_DEG)[d] = dg;
        float di = rsqrtf((float)dg);
        ws[WS_DINV + d] = di;
        float2 gv = reinterpret_cast<const float2*>(ws + WS_G)[d];
        unsigned int lo = (unsigned int)__float2int_rn((gv.x * di + FXB) * FXS);
        unsigned int hi = (unsigned int)__float2int_rn((gv.y * di + FXB) * FXS);
        reinterpret_cast<unsigned long long*>(ws + WS_FXP)[d] =
            ((unsigned long long)hi << 32) | (unsigned long long)lo;
    }
}

// ---- kernel 4: per-bin LDS u64 accumulation of fxp[src] over shards ----
__global__ __launch_bounds__(512) void k_pass2(float* __restrict__ ws,
                                               float2* __restrict__ out) {
    int b = blockIdx.x;
    int tid = threadIdx.x;
    const int* gcur = reinterpret_cast<const int*>(ws + WS_CUR);
    const unsigned int* bins = reinterpret_cast<const unsigned int*>(ws + WS_BINS);
    const int* deg = reinterpret_cast<const int*>(ws + WS_DEG);
    const float* dinv = ws + WS_DINV;
    const unsigned long long* fxp = reinterpret_cast<const unsigned long long*>(ws + WS_FXP);
    __shared__ unsigned long long acc[BINW];
    if (tid < BINW) acc[tid] = 0ull;
    __syncthreads();
    #pragma unroll
    for (int sg = 0; sg < NSH; ++sg) {
        int cell = b * NSH + sg;
        int n = min(gcur[cell], BCAP_S);
        const unsigned int* bb = bins + (size_t)cell * BCAP_S;
        for (int i = tid; i < n; i += 512) {
            unsigned int p = bb[i];
            atomicAdd(&acc[p >> 17], fxp[p & 0x1FFFFu]);
        }
    }
    __syncthreads();
    int d = (b << BSH) + tid;
    if (tid < BINW && d < N_NODES) {
        unsigned long long a = acc[tid] + fxp[d];    // + self-loop addend
        long long dg = (long long)deg[d];
        long long bias = dg << 25;                   // exact: deg * FXB*FXS
        long long lo = (long long)(a & 0xFFFFFFFFull) - bias;
        long long hi = (long long)(a >> 32) - bias;
        float di = dinv[d];
        out[d] = make_float2(di * ((float)lo * (1.0f / FXS)) + ws[WS_C + 0],
                             di * ((float)hi * (1.0f / FXS)) + ws[WS_C + 1]);
    }
}

extern "C" void kernel_launch(void* const* d_in, const int* in_sizes, int n_in,
                              void* d_out, int out_size, void* d_ws, size_t ws_size,
                              hipStream_t stream) {
    const float* x  = (const float*)d_in[0];
    const float* w1 = (const float*)d_in[1];
    const float* b1 = (const float*)d_in[2];
    const float* w2 = (const float*)d_in[3];
    const float* b2 = (const float*)d_in[4];
    const int*   ei = (const int*)d_in[5];   // [2, E]: src row then dst row
    float* ws = (float*)d_ws;

    float2* g = (float2*)(ws + WS_G);

    k_prep<<<13, 256, 0, stream>>>(w1, w2, b1, b2, ws);
    k_fused<<<GRID, 256, 0, stream>>>(x, ws, ei, ei + N_EDGES, g);
    k_deg<<<NBINS, 512, 0, stream>>>(ws);
    k_pass2<<<NBINS, 512, 0, stream>>>(ws, (float2*)d_out);
}